// Round 7
// baseline (321.500 us; speedup 1.0000x reference)
//
#include <hip/hip_runtime.h>

#define BB 32
#define NP 2048
#define NG 2048
#define EPSF 1e-6f
#define BIGF 1e18f
#define FLTMAX 3.4e38f
#define MT 128   // m-tile staged in LDS per block
#define MP 16    // partials per side
#define TPT 4    // points per thread

// ws layout:
//  [0, 8448)     : fpart[264][8] floats (per-fin-block partial sums)
//  [16384, +8)   : 2 u32 semaphore counters (memset to 0 each call)
//  [65536, +8MB) : pred partials u64 [b][mp][n] (dist_bits<<32 | idx)
//  [+8MB, +4MB)  : tgt partials f32 [b][np][m]
#define FPART_OFF 0
#define CTR_OFF 16384
#define PPART_OFF 65536
#define TPART_OFF (65536 + BB * MP * NP * 8)

// Single fused kernel. grid=2048 blocks of 256, __launch_bounds__(256,8)
// forces <=64 VGPR -> 8 blocks/CU -> total capacity 256*8 = 2048 >= grid, so
// every block is resident and semaphore spin cannot deadlock.
// Phase 1 (all blocks): pairwise min partials.
//   blocks [0,1024): pred side (masked min+argmin over targets)
//   blocks [1024,2048): tgt side (unmasked min over preds)
// Gate A: all 2048 blocks signal ctr[0]; blocks >=264 exit.
// Phase 1.5 (fin blocks, pre-gate): input-only sums (entropy/hit/E*hit/mask/kld)
//   overlapped with other blocks' phase-1 work.
// Phase 2 (fin blocks, post-gate): partial-dependent sums -> fpart.
// Gate B: 264 fin blocks signal ctr[1]; block 0 assembles the 6 outputs.
__global__ __launch_bounds__(256, 8) void k_all(const float* __restrict__ preds,
                                                const float* __restrict__ target,
                                                const float* __restrict__ mask,
                                                const float* __restrict__ mu,
                                                const float* __restrict__ logvar,
                                                const float* __restrict__ e_init,
                                                const float* __restrict__ kl_weight,
                                                unsigned long long* __restrict__ ppart,
                                                float* __restrict__ tpart,
                                                float* __restrict__ fpart,
                                                unsigned* __restrict__ ctr,
                                                float* __restrict__ out) {
  __shared__ float4 s4[MT];
  __shared__ float red[4][8];
  const int bx = blockIdx.x;
  const int tid = threadIdx.x;
  const int wave = tid >> 6, lane = tid & 63;

  // ---------------- Phase 1: pairwise partials ----------------
  if (bx < 1024) {
    const int b = bx >> 5;
    const int nch = (bx >> 4) & 1;
    const int mp = bx & 15;
    const float* tb = target + b * 4 * NG;
    const int mbase = mp * MT;
    if (tid < MT) {
      int m = mbase + tid;
      float tx = tb[m], ty = tb[NG + m], tz = tb[2 * NG + m];
      float tn = fmaf(tx, tx, fmaf(ty, ty, tz * tz));
      float w = tn + (mask[b * NG + m] == 0.0f ? BIGF : 0.0f);  // fold BIG mask
      s4[tid] = make_float4(-2.0f * tx, -2.0f * ty, -2.0f * tz, w);
    }
    __syncthreads();

    const float* pb = preds + b * 5 * NP;
    const int nbase = nch * 1024 + tid;
    float px[TPT], py[TPT], pz[TPT], bv[TPT];
    int bi[TPT];
#pragma unroll
    for (int k = 0; k < TPT; k++) {
      int n = nbase + k * 256;
      px[k] = pb[n];
      py[k] = pb[NP + n];
      pz[k] = pb[2 * NP + n];
      bv[k] = FLTMAX;
      bi[k] = 0;
    }
    // s = tn - 2*dot (+BIG if masked); pn^2 thread-invariant -> folded out.
#pragma unroll 4
    for (int m = 0; m < MT; m++) {
      float4 t = s4[m];
#pragma unroll
      for (int k = 0; k < TPT; k++) {
        float s = fmaf(px[k], t.x, fmaf(py[k], t.y, fmaf(pz[k], t.z, t.w)));
        if (s < bv[k]) { bv[k] = s; bi[k] = m; }  // strict < keeps first index
      }
    }
    unsigned long long* row = &ppart[(b * MP + mp) * NP];
#pragma unroll
    for (int k = 0; k < TPT; k++) {
      float pn = fmaf(px[k], px[k], fmaf(py[k], py[k], pz[k] * pz[k]));
      float d = fmaxf(bv[k] + pn, 0.0f);
      row[nbase + k * 256] =
          ((unsigned long long)__float_as_uint(d) << 32) | (unsigned)(mbase + bi[k]);
    }
  } else {
    const int bb = bx - 1024;
    const int b = bb >> 5;
    const int mch = (bb >> 4) & 1;
    const int np_ = bb & 15;
    const float* pb = preds + b * 5 * NP;
    if (tid < MT) {
      int n = np_ * MT + tid;
      float px = pb[n], py = pb[NP + n], pz = pb[2 * NP + n];
      float pn2 = fmaf(px, px, fmaf(py, py, pz * pz));
      s4[tid] = make_float4(-2.0f * px, -2.0f * py, -2.0f * pz, pn2);
    }
    __syncthreads();

    const float* tb = target + b * 4 * NG;
    const int mbase2 = mch * 1024 + tid;
    float tx[TPT], ty[TPT], tz[TPT], cv[TPT];
#pragma unroll
    for (int k = 0; k < TPT; k++) {
      int m = mbase2 + k * 256;
      tx[k] = tb[m];
      ty[k] = tb[NG + m];
      tz[k] = tb[2 * NG + m];
      cv[k] = FLTMAX;
    }
#pragma unroll 4
    for (int n = 0; n < MT; n++) {
      float4 p = s4[n];
#pragma unroll
      for (int k = 0; k < TPT; k++)
        cv[k] = fminf(cv[k], fmaf(tx[k], p.x, fmaf(ty[k], p.y, fmaf(tz[k], p.z, p.w))));
    }
    float* row = &tpart[(b * MP + np_) * NG];
#pragma unroll
    for (int k = 0; k < TPT; k++) {
      float tn = fmaf(tx[k], tx[k], fmaf(ty[k], ty[k], tz[k] * tz[k]));
      row[mbase2 + k * 256] = fmaxf(cv[k] + tn, 0.0f);
    }
  }

  // ---------------- Gate A signal ----------------
  __threadfence();   // make this thread's partial stores device-visible
  __syncthreads();   // all waves' fences done
  if (tid == 0) atomicAdd(&ctr[0], 1u);
  if (bx >= 264) return;

  // ---------------- Phase 1.5: input-only sums (overlaps others' phase 1) ----
  float q0 = 0.0f, q1 = 0.0f, q2 = 0.0f, q3 = 0.0f, q4 = 0.0f;
  float sv0 = 0.0f, sv1 = 0.0f;  // saved across gate: pE[e] or msk[e]
  float sh0 = 0.0f, sh1 = 0.0f;  // saved ph[e] (pred role)
  if (bx < 128) {
    const int b = bx >> 2;
    const float* pb = preds + b * 5 * NP;
    {
      int n = (bx * 512 + tid) & 2047;
      sv0 = pb[3 * NP + n];
      sh0 = pb[4 * NP + n];
      int n1 = (bx * 512 + 256 + tid) & 2047;
      sv1 = pb[3 * NP + n1];
      sh1 = pb[4 * NP + n1];
    }
    q2 += sh0 * logf(sh0 + EPSF) + (1.0f - sh0) * logf(1.0f - sh0 + EPSF);
    q2 += sh1 * logf(sh1 + EPSF) + (1.0f - sh1) * logf(1.0f - sh1 + EPSF);
    q3 = sh0 + sh1;
    q4 = sv0 * sh0 + sv1 * sh1;
  } else if (bx < 256) {
    const int bb = bx - 128;
    sv0 = mask[bb * 512 + tid];
    sv1 = mask[bb * 512 + 256 + tid];
    q1 = sv0 + sv1;  // global mask sum
    q2 = sv0 + sv1;  // per-b mask sum (separate slot)
  } else {
    const int bb = bx - 256;  // B*L = 8192 over 8 blocks
#pragma unroll
    for (int e = 0; e < 4; e++) {
      int i = bb * 1024 + e * 256 + tid;
      float m = mu[i], lv = logvar[i];
      q0 += 1.0f + lv - m * m - expf(lv);
    }
  }

  // ---------------- Gate A wait ----------------
  if (tid == 0) {
    while (atomicAdd(&ctr[0], 0u) < 2048u) __builtin_amdgcn_s_sleep(4);
  }
  __syncthreads();
  __threadfence();  // acquire: invalidate stale lines before reading partials

  // ---------------- Phase 2: partial-dependent sums ----------------
  if (bx < 128) {
    const int b = bx >> 2;
    const float* te = target + b * 4 * NG + 3 * NG;
#pragma unroll
    for (int e = 0; e < 2; e++) {
      int n = (bx * 512 + e * 256 + tid) & 2047;
      unsigned long long best = 0xFFFFFFFFFFFFFFFFull;
      const unsigned long long* col = &ppart[b * MP * NP + n];
#pragma unroll
      for (int mp = 0; mp < MP; mp++) {
        unsigned long long v = col[mp * NP];  // coalesced across lanes
        best = v < best ? v : best;           // min packed: dist then index
      }
      q0 += __uint_as_float((unsigned)(best >> 32));
      float pE = e ? sv1 : sv0;
      q1 += fabsf(pE - te[(int)(best & 0xffffffffu)]);
    }
  } else if (bx < 256) {
    const int bb = bx - 128;
    const int b = bb >> 2;
#pragma unroll
    for (int e = 0; e < 2; e++) {
      int m = (bb * 512 + e * 256 + tid) & 2047;
      float d = FLTMAX;
      const float* col = &tpart[b * MP * NG + m];
#pragma unroll
      for (int np_ = 0; np_ < MP; np_++) d = fminf(d, col[np_ * NG]);
      q0 += d * (e ? sv1 : sv0);  // sum min_dist_tgt * mask
    }
  }

  // ---------------- block reduction -> fpart ----------------
  float qs[5] = {q0, q1, q2, q3, q4};
  for (int k = 0; k < 5; k++) {
    float v = qs[k];
    v += __shfl_down(v, 32);
    v += __shfl_down(v, 16);
    v += __shfl_down(v, 8);
    v += __shfl_down(v, 4);
    v += __shfl_down(v, 2);
    v += __shfl_down(v, 1);
    if (lane == 0) red[wave][k] = v;
  }
  __syncthreads();
  if (tid < 5) fpart[bx * 8 + tid] = red[0][tid] + red[1][tid] + red[2][tid] + red[3][tid];
  __threadfence();
  __syncthreads();
  if (tid == 0) atomicAdd(&ctr[1], 1u);
  if (bx != 0) return;

  // ---------------- Gate B wait + final assembly (block 0) ----------------
  if (tid == 0) {
    while (atomicAdd(&ctr[1], 0u) < 264u) __builtin_amdgcn_s_sleep(4);
  }
  __syncthreads();
  __threadfence();

  float g[8] = {0, 0, 0, 0, 0, 0, 0, 0};
  // g0 sum_min_pred, g1 sum|dE|, g2 entropy, g3 sum d*msk, g4 mask_sum,
  // g5 kld_sum, g6 hit_sq_sum, g7 esq_sum
  if (tid < 128) {
    const float* r = &fpart[tid * 8];
    g[0] = r[0]; g[1] = r[1]; g[2] = r[2];
    const float* r2 = &fpart[(128 + tid) * 8];
    g[3] = r2[0]; g[4] = r2[1];
  }
  if (tid < 8) g[5] = fpart[(256 + tid) * 8];
  if (tid < BB) {
    float hit = 0.0f, eh = 0.0f, mk = 0.0f;
#pragma unroll
    for (int k = 0; k < 4; k++) {
      hit += fpart[(4 * tid + k) * 8 + 3];
      eh += fpart[(4 * tid + k) * 8 + 4];
      mk += fpart[(128 + 4 * tid + k) * 8 + 2];
    }
    float dh = hit - mk;
    g[6] = dh * dh;
    float de = eh - e_init[tid];
    g[7] = de * de;
  }
  for (int k = 0; k < 8; k++) {
    float v = g[k];
    v += __shfl_down(v, 32);
    v += __shfl_down(v, 16);
    v += __shfl_down(v, 8);
    v += __shfl_down(v, 4);
    v += __shfl_down(v, 2);
    v += __shfl_down(v, 1);
    if (lane == 0) red[wave][k] = v;
  }
  __syncthreads();
  if (tid == 0) {
    float s[8];
    for (int k = 0; k < 8; k++) s[k] = red[0][k] + red[1][k] + red[2][k] + red[3][k];
    const float invBN = 1.0f / (float)(BB * NP);
    float chamfer_pred = s[0] * invBN;
    float localE = s[1] * invBN;
    float ent = -s[2] * invBN;
    float chamfer_tgt = s[3] / s[4];
    float kld = -0.5f * s[5] / (float)BB;
    float hit = s[6] / (float)BB;
    float ge = s[7] / (float)BB;

    float loss_chamf = (chamfer_tgt + chamfer_pred) * 0.001f;  // LAMBDA_CHAMFER
    float losskld = kl_weight[0] * kld;
    float loss_ge = 10.0f * ge;    // LAMBDA_E_SUM
    float loss_hit = 20.0f * hit;  // LAMBDA_HIT
    float loss_ent = 0.1f * ent;   // LAMBDA_HIT_ENTROPY

    float total = loss_chamf + localE + losskld + loss_ge + loss_hit + loss_ent;
    out[0] = total;
    out[1] = loss_chamf;
    out[2] = localE;
    out[3] = loss_ge;
    out[4] = loss_hit;
    out[5] = losskld;
  }
}

extern "C" void kernel_launch(void* const* d_in, const int* in_sizes, int n_in,
                              void* d_out, int out_size, void* d_ws, size_t ws_size,
                              hipStream_t stream) {
  const float* preds = (const float*)d_in[0];
  const float* target = (const float*)d_in[1];
  const float* mask = (const float*)d_in[2];
  const float* mu = (const float*)d_in[3];
  const float* logvar = (const float*)d_in[4];
  const float* e_init = (const float*)d_in[5];
  const float* kl_weight = (const float*)d_in[6];
  float* fpart = (float*)((char*)d_ws + FPART_OFF);
  unsigned* ctr = (unsigned*)((char*)d_ws + CTR_OFF);
  unsigned long long* ppart = (unsigned long long*)((char*)d_ws + PPART_OFF);
  float* tpart = (float*)((char*)d_ws + TPART_OFF);
  float* out = (float*)d_out;

  hipMemsetAsync(ctr, 0, 2 * sizeof(unsigned), stream);
  k_all<<<2048, 256, 0, stream>>>(preds, target, mask, mu, logvar, e_init,
                                  kl_weight, ppart, tpart, fpart, ctr, out);
}

// Round 8
// 105.624 us; speedup vs baseline: 3.0438x; 3.0438x over previous
//
#include <hip/hip_runtime.h>

#define BB 32
#define NP 2048
#define NG 2048
#define EPSF 1e-6f
#define BIGF 1e18f
#define FLTMAX 3.4e38f
#define MT 128   // m-tile staged in LDS per block
#define MP 16    // partials per side
#define TPT 8    // points per thread; ~52 live VGPR -> fits 64-VGPR/8-wave budget

// ws layout (all regions fully overwritten every call -> no init memsets):
//  [0, 8448)            : fpart[264][8] floats (k_fin per-block partial sums)
//  [65536, +8MB)        : pred partials u64 [b][mp][n]  (dist_bits<<32 | idx)
//  [65536+8MB, +4MB)    : tgt partials f32 [b][np][m]
#define FPART_OFF 0
#define PPART_OFF 65536
#define TPART_OFF (65536 + BB * MP * NP * 8)

// Fused pairwise kernel. Blocks [0,512): pred side (masked min+argmin over
// targets); blocks [512,1024): tgt side (unmasked min over preds).
// Per side: 32 b * 16 mp; each thread owns 8 points (stride 256) so one
// ds_read_b128 broadcast feeds 8 pairs (LDS-issue ~10us model), and
// launch_bounds(256,8) caps VGPR at 64 -> 8 waves/SIMD for latency hiding.
// NOTE (R7 lesson): do NOT fuse these stages with device fences — each
// __threadfence() on gfx950 is an L2 writeback+invalidate (non-coherent
// per-XCD L2s); 2048 of them cost ~260us. Kernel boundaries flush once.
__global__ __launch_bounds__(256, 8) void k_pair(const float* __restrict__ preds,
                                                 const float* __restrict__ target,
                                                 const float* __restrict__ mask,
                                                 unsigned long long* __restrict__ ppart,
                                                 float* __restrict__ tpart) {
  __shared__ float4 s4[MT];
  const int bx = blockIdx.x;
  const int tid = threadIdx.x;

  if (bx < 512) {
    // ---- pred side ----
    const int b = bx >> 4;
    const int mp = bx & 15;
    const float* tb = target + b * 4 * NG;
    const int mbase = mp * MT;
    if (tid < MT) {
      int m = mbase + tid;
      float tx = tb[m], ty = tb[NG + m], tz = tb[2 * NG + m];
      float tn = fmaf(tx, tx, fmaf(ty, ty, tz * tz));
      float w = tn + (mask[b * NG + m] == 0.0f ? BIGF : 0.0f);  // fold BIG mask
      s4[tid] = make_float4(-2.0f * tx, -2.0f * ty, -2.0f * tz, w);
    }
    __syncthreads();

    const float* pb = preds + b * 5 * NP;
    float px[TPT], py[TPT], pz[TPT], bv[TPT];
    int bi[TPT];
#pragma unroll
    for (int k = 0; k < TPT; k++) {
      int n = tid + k * 256;
      px[k] = pb[n];
      py[k] = pb[NP + n];
      pz[k] = pb[2 * NP + n];
      bv[k] = FLTMAX;
      bi[k] = 0;
    }

    // s = tn - 2*dot (+BIG if masked); pn^2 thread-invariant -> folded out.
#pragma unroll 2
    for (int m = 0; m < MT; m++) {
      float4 t = s4[m];
#pragma unroll
      for (int k = 0; k < TPT; k++) {
        float s = fmaf(px[k], t.x, fmaf(py[k], t.y, fmaf(pz[k], t.z, t.w)));
        if (s < bv[k]) { bv[k] = s; bi[k] = m; }  // strict < keeps first index
      }
    }

    unsigned long long* row = &ppart[(b * MP + mp) * NP];
#pragma unroll
    for (int k = 0; k < TPT; k++) {
      float pn = fmaf(px[k], px[k], fmaf(py[k], py[k], pz[k] * pz[k]));
      float d = fmaxf(bv[k] + pn, 0.0f);
      row[tid + k * 256] =
          ((unsigned long long)__float_as_uint(d) << 32) | (unsigned)(mbase + bi[k]);
    }
  } else {
    // ---- tgt side ----
    const int bb = bx - 512;
    const int b = bb >> 4;
    const int np_ = bb & 15;
    const float* pb = preds + b * 5 * NP;
    if (tid < MT) {
      int n = np_ * MT + tid;
      float px = pb[n], py = pb[NP + n], pz = pb[2 * NP + n];
      float pn2 = fmaf(px, px, fmaf(py, py, pz * pz));
      s4[tid] = make_float4(-2.0f * px, -2.0f * py, -2.0f * pz, pn2);
    }
    __syncthreads();

    const float* tb = target + b * 4 * NG;
    float tx[TPT], ty[TPT], tz[TPT], cv[TPT];
#pragma unroll
    for (int k = 0; k < TPT; k++) {
      int m = tid + k * 256;
      tx[k] = tb[m];
      ty[k] = tb[NG + m];
      tz[k] = tb[2 * NG + m];
      cv[k] = FLTMAX;
    }

#pragma unroll 2
    for (int n = 0; n < MT; n++) {
      float4 p = s4[n];
#pragma unroll
      for (int k = 0; k < TPT; k++)
        cv[k] = fminf(cv[k], fmaf(tx[k], p.x, fmaf(ty[k], p.y, fmaf(tz[k], p.z, p.w))));
    }

    float* row = &tpart[(b * MP + np_) * NG];
#pragma unroll
    for (int k = 0; k < TPT; k++) {
      float tn = fmaf(tx[k], tx[k], fmaf(ty[k], ty[k], tz[k] * tz[k]));
      row[tid + k * 256] = fmaxf(cv[k] + tn, 0.0f);
    }
  }
}

// Combine: blocks [0,128) pred side, [128,256) tgt side, [256,264) kld.
// Reduces 16 partials per point, computes elementwise pieces, block-level
// LDS reduction, writes 5 partial sums to a private slot (no atomics).
__global__ __launch_bounds__(256) void k_fin(const unsigned long long* __restrict__ ppart,
                                             const float* __restrict__ tpart,
                                             const float* __restrict__ preds,
                                             const float* __restrict__ target,
                                             const float* __restrict__ mask,
                                             const float* __restrict__ mu,
                                             const float* __restrict__ logvar,
                                             float* __restrict__ fpart) {
  __shared__ float red[4][8];
  const int bx = blockIdx.x;
  const int tid = threadIdx.x;
  const int wave = tid >> 6, lane = tid & 63;
  float q0 = 0.0f, q1 = 0.0f, q2 = 0.0f, q3 = 0.0f, q4 = 0.0f;

  if (bx < 128) {
    const int b = bx >> 2;
    const float* pb = preds + b * 5 * NP;
    const float* te = target + b * 4 * NG + 3 * NG;
#pragma unroll
    for (int e = 0; e < 2; e++) {
      int i = bx * 512 + e * 256 + tid;
      int n = i & 2047;
      unsigned long long best = 0xFFFFFFFFFFFFFFFFull;
      const unsigned long long* col = &ppart[b * MP * NP + n];
#pragma unroll
      for (int mp = 0; mp < MP; mp++) {
        unsigned long long v = col[mp * NP];  // coalesced across lanes
        best = v < best ? v : best;           // min packed: dist then index
      }
      float bd = __uint_as_float((unsigned)(best >> 32));
      int idx = (int)(best & 0xffffffffu);
      float mE = te[idx];
      float pE = pb[3 * NP + n];
      float ph = pb[4 * NP + n];
      q0 += bd;
      q1 += fabsf(pE - mE);
      q2 += ph * logf(ph + EPSF) + (1.0f - ph) * logf(1.0f - ph + EPSF);
      q3 += ph;
      q4 += pE * ph;
    }
  } else if (bx < 256) {
    const int bb = bx - 128;
    const int b = bb >> 2;
#pragma unroll
    for (int e = 0; e < 2; e++) {
      int i = bb * 512 + e * 256 + tid;
      int m = i & 2047;
      float d = FLTMAX;
      const float* col = &tpart[b * MP * NG + m];
#pragma unroll
      for (int np_ = 0; np_ < MP; np_++) d = fminf(d, col[np_ * NG]);
      float msk = mask[i];
      q0 += d * msk;  // sum min_dist_tgt * mask
      q1 += msk;      // global mask sum
      q2 += msk;      // per-b mask sum (same value, separate slot)
    }
  } else {
    const int bb = bx - 256;  // B*L = 8192 over 8 blocks
#pragma unroll
    for (int e = 0; e < 4; e++) {
      int i = bb * 1024 + e * 256 + tid;
      float m = mu[i], lv = logvar[i];
      q0 += 1.0f + lv - m * m - expf(lv);
    }
  }

  float qs[5] = {q0, q1, q2, q3, q4};
  for (int k = 0; k < 5; k++) {
    float v = qs[k];
    v += __shfl_down(v, 32);
    v += __shfl_down(v, 16);
    v += __shfl_down(v, 8);
    v += __shfl_down(v, 4);
    v += __shfl_down(v, 2);
    v += __shfl_down(v, 1);
    if (lane == 0) red[wave][k] = v;
  }
  __syncthreads();
  if (tid < 5) fpart[bx * 8 + tid] = red[0][tid] + red[1][tid] + red[2][tid] + red[3][tid];
}

// Single-block final reduction over fpart rows + loss assembly.
__global__ __launch_bounds__(256) void k_final(const float* __restrict__ fpart,
                                               const float* __restrict__ e_init,
                                               const float* __restrict__ kl_weight,
                                               float* __restrict__ out) {
  __shared__ float red[4][8];
  const int t = threadIdx.x;
  const int wave = t >> 6, lane = t & 63;
  float g[8] = {0, 0, 0, 0, 0, 0, 0, 0};
  // g0 sum_min_pred, g1 sum|dE|, g2 entropy, g3 sum d*msk, g4 mask_sum,
  // g5 kld_sum, g6 hit_sq_sum, g7 esq_sum
  if (t < 128) {
    const float* r = &fpart[t * 8];
    g[0] = r[0]; g[1] = r[1]; g[2] = r[2];
    const float* r2 = &fpart[(128 + t) * 8];
    g[3] = r2[0]; g[4] = r2[1];
  }
  if (t < 8) g[5] = fpart[(256 + t) * 8];
  if (t < BB) {
    float hit = 0.0f, eh = 0.0f, mk = 0.0f;
#pragma unroll
    for (int k = 0; k < 4; k++) {
      hit += fpart[(4 * t + k) * 8 + 3];
      eh += fpart[(4 * t + k) * 8 + 4];
      mk += fpart[(128 + 4 * t + k) * 8 + 2];
    }
    float dh = hit - mk;
    g[6] = dh * dh;
    float de = eh - e_init[t];
    g[7] = de * de;
  }
  for (int k = 0; k < 8; k++) {
    float v = g[k];
    v += __shfl_down(v, 32);
    v += __shfl_down(v, 16);
    v += __shfl_down(v, 8);
    v += __shfl_down(v, 4);
    v += __shfl_down(v, 2);
    v += __shfl_down(v, 1);
    if (lane == 0) red[wave][k] = v;
  }
  __syncthreads();
  if (t == 0) {
    float s[8];
    for (int k = 0; k < 8; k++) s[k] = red[0][k] + red[1][k] + red[2][k] + red[3][k];
    const float invBN = 1.0f / (float)(BB * NP);
    float chamfer_pred = s[0] * invBN;
    float localE = s[1] * invBN;
    float ent = -s[2] * invBN;
    float chamfer_tgt = s[3] / s[4];
    float kld = -0.5f * s[5] / (float)BB;
    float hit = s[6] / (float)BB;
    float ge = s[7] / (float)BB;

    float loss_chamf = (chamfer_tgt + chamfer_pred) * 0.001f;  // LAMBDA_CHAMFER
    float losskld = kl_weight[0] * kld;
    float loss_ge = 10.0f * ge;    // LAMBDA_E_SUM
    float loss_hit = 20.0f * hit;  // LAMBDA_HIT
    float loss_ent = 0.1f * ent;   // LAMBDA_HIT_ENTROPY

    float total = loss_chamf + localE + losskld + loss_ge + loss_hit + loss_ent;
    out[0] = total;
    out[1] = loss_chamf;
    out[2] = localE;
    out[3] = loss_ge;
    out[4] = loss_hit;
    out[5] = losskld;
  }
}

extern "C" void kernel_launch(void* const* d_in, const int* in_sizes, int n_in,
                              void* d_out, int out_size, void* d_ws, size_t ws_size,
                              hipStream_t stream) {
  const float* preds = (const float*)d_in[0];
  const float* target = (const float*)d_in[1];
  const float* mask = (const float*)d_in[2];
  const float* mu = (const float*)d_in[3];
  const float* logvar = (const float*)d_in[4];
  const float* e_init = (const float*)d_in[5];
  const float* kl_weight = (const float*)d_in[6];
  float* fpart = (float*)((char*)d_ws + FPART_OFF);
  unsigned long long* ppart = (unsigned long long*)((char*)d_ws + PPART_OFF);
  float* tpart = (float*)((char*)d_ws + TPART_OFF);
  float* out = (float*)d_out;

  k_pair<<<1024, 256, 0, stream>>>(preds, target, mask, ppart, tpart);
  k_fin<<<264, 256, 0, stream>>>(ppart, tpart, preds, target, mask, mu, logvar, fpart);
  k_final<<<1, 256, 0, stream>>>(fpart, e_init, kl_weight, out);
}